// Round 3
// baseline (690.061 us; speedup 1.0000x reference)
//
#include <hip/hip_runtime.h>

#define DIM 1024
#define HID 2048
#define NE 8
#define LR 16
#define T_TOK 2048
#define NROWS 4096
#define BM 128
#define BN 64
#define BK 64
#define MAX_MT 40
#define ROWS_PAD (NROWS + BM)

typedef __attribute__((ext_vector_type(8))) short bf16x8;
typedef __attribute__((ext_vector_type(4))) float f32x4;

__device__ __forceinline__ unsigned short f2bf(float f) {
  unsigned u = __builtin_bit_cast(unsigned, f);
  u += 0x7FFFu + ((u >> 16) & 1u);
  return (unsigned short)(u >> 16);
}

__device__ __forceinline__ void gload_lds16(const void* g, void* l) {
  __builtin_amdgcn_global_load_lds(
      (const __attribute__((address_space(1))) unsigned int*)g,
      (__attribute__((address_space(3))) unsigned int*)l, 16, 0, 0);
}

// ---------------- routing: logits -> top2 -> gates -------------------------
__global__ void routing_kernel(const float* __restrict__ x, const float* __restrict__ Wg,
                               int* __restrict__ counts, int* __restrict__ topk_idx,
                               float* __restrict__ topk_gate) {
  int t = blockIdx.x * 4 + (threadIdx.x >> 6);
  int lane = threadIdx.x & 63;
  const float* xr = x + (size_t)t * DIM;
  float xa[16];
#pragma unroll
  for (int i = 0; i < 16; i++) xa[i] = xr[lane + 64 * i];
  float lg[NE];
#pragma unroll
  for (int e = 0; e < NE; e++) {
    const float* wr_ = Wg + e * DIM;
    float s = 0.f;
#pragma unroll
    for (int i = 0; i < 16; i++) s += xa[i] * wr_[lane + 64 * i];
#pragma unroll
    for (int off = 32; off > 0; off >>= 1) s += __shfl_xor(s, off);
    lg[e] = s;
  }
  if (lane == 0) {
    int i0 = 0;
#pragma unroll
    for (int e = 1; e < NE; e++) if (lg[e] > lg[i0]) i0 = e;
    int i1 = (i0 == 0) ? 1 : 0;
#pragma unroll
    for (int e = 0; e < NE; e++) if (e != i0 && lg[e] > lg[i1]) i1 = e;
    float e1 = __expf(lg[i1] - lg[i0]);
    float inv = 1.f / (1.f + e1);
    topk_idx[2 * t] = i0;
    topk_idx[2 * t + 1] = i1;
    topk_gate[2 * t] = inv;
    topk_gate[2 * t + 1] = e1 * inv;
    atomicAdd(&counts[i0], 1);
    atomicAdd(&counts[i1], 1);
  }
}

// ---------------- scan: offsets + tile schedule ----------------------------
__global__ void scan_kernel(const int* __restrict__ counts, int* __restrict__ offsets,
                            int* __restrict__ nmt, int* __restrict__ tiles) {
  if (threadIdx.x == 0) {
    int off = 0, nt = 0;
    for (int e = 0; e < NE; e++) {
      offsets[e] = off;
      int c = counts[e];
      for (int mm = 0; mm * BM < c; mm++) tiles[nt++] = (e << 16) | mm;
      off += c;
    }
    offsets[NE] = off;
    nmt[0] = nt;
  }
}

// ---------------- scatter: (t,slot) -> compact row -------------------------
__global__ void scatter_kernel(const int* __restrict__ topk_idx,
                               const int* __restrict__ offsets, int* __restrict__ cursors,
                               int* __restrict__ perm, int* __restrict__ rowexp,
                               int* __restrict__ pos) {
  int i = blockIdx.x * 256 + threadIdx.x;
  int e = topk_idx[i];
  int r = offsets[e] + atomicAdd(&cursors[e], 1);
  perm[r] = i >> 1;
  rowexp[r] = e;
  pos[i] = r;
}

// ---------------- gather x rows (bf16) + t1=xA1^T, t3=xA3^T ----------------
__global__ void gather_lora13_kernel(const float* __restrict__ x,
                                     const float* __restrict__ A1, const float* __restrict__ A3,
                                     const int* __restrict__ perm, const int* __restrict__ rowexp,
                                     unsigned short* __restrict__ Xg,
                                     float* __restrict__ t1g, float* __restrict__ t3g) {
  __shared__ float xs[DIM];
  int r = blockIdx.x;
  int t = perm[r], e = rowexp[r];
  int tid = threadIdx.x;
  float4 v = ((const float4*)(x + (size_t)t * DIM))[tid];
  ((float4*)xs)[tid] = v;
  ushort4 hv;
  hv.x = f2bf(v.x); hv.y = f2bf(v.y); hv.z = f2bf(v.z); hv.w = f2bf(v.w);
  ((ushort4*)(Xg + (size_t)r * DIM))[tid] = hv;
  __syncthreads();
  int w = tid >> 6, lane = tid & 63;
  const float* A = ((w < 2) ? A1 : A3) + (size_t)e * LR * DIM + (size_t)((w & 1) * 8) * DIM;
  float* tout = ((w < 2) ? t1g : t3g) + (size_t)r * LR + (w & 1) * 8;
  float acc[8];
#pragma unroll
  for (int j = 0; j < 8; j++) acc[j] = 0.f;
  for (int i = 0; i < 16; i++) {
    float xv = xs[lane + 64 * i];
#pragma unroll
    for (int j = 0; j < 8; j++) acc[j] += xv * A[(size_t)j * DIM + lane + 64 * i];
  }
#pragma unroll
  for (int j = 0; j < 8; j++) {
    float s = acc[j];
#pragma unroll
    for (int off = 32; off > 0; off >>= 1) s += __shfl_xor(s, off);
    if (lane == 0) tout[j] = s;
  }
}

// ---------------- t2 = g A2^T ----------------------------------------------
__global__ void lora2_kernel(const unsigned short* __restrict__ gb,
                             const float* __restrict__ A2, const int* __restrict__ rowexp,
                             float* __restrict__ t2g) {
  __shared__ float gs[HID];
  int r = blockIdx.x, tid = threadIdx.x;
  int e = rowexp[r];
  uint4 raw = ((const uint4*)(gb + (size_t)r * HID))[tid];
  unsigned u[4] = {raw.x, raw.y, raw.z, raw.w};
#pragma unroll
  for (int k = 0; k < 4; k++) {
    gs[tid * 8 + 2 * k] = __builtin_bit_cast(float, u[k] << 16);
    gs[tid * 8 + 2 * k + 1] = __builtin_bit_cast(float, u[k] & 0xffff0000u);
  }
  __syncthreads();
  int w = tid >> 6, lane = tid & 63;
  const float* A = A2 + (size_t)e * LR * HID + (size_t)(w * 4) * HID;
  float acc[4];
#pragma unroll
  for (int j = 0; j < 4; j++) acc[j] = 0.f;
  for (int i = 0; i < HID / 64; i++) {
    float xv = gs[lane + 64 * i];
#pragma unroll
    for (int j = 0; j < 4; j++) acc[j] += xv * A[(size_t)j * HID + lane + 64 * i];
  }
#pragma unroll
  for (int j = 0; j < 4; j++) {
    float s = acc[j];
#pragma unroll
    for (int off = 32; off > 0; off >>= 1) s += __shfl_xor(s, off);
    if (lane == 0) t2g[(size_t)r * LR + w * 4 + j] = s;
  }
}

// ---------------- GEMM1: g = silu(Xg W1^T + lora + b1) * (Xg W3^T + lora + b3)
__global__ __launch_bounds__(256) void gemm1_dual(
    const unsigned short* __restrict__ Xg,
    const float* __restrict__ W1, const float* __restrict__ W3,
    const float* __restrict__ b1, const float* __restrict__ b3,
    const float* __restrict__ B1l, const float* __restrict__ B3l,
    const float* __restrict__ t1g, const float* __restrict__ t3g,
    const int* __restrict__ offsets, const int* __restrict__ nmt,
    const int* __restrict__ tiles,
    unsigned short* __restrict__ g) {
  int ntid = blockIdx.x & 31;   // HID/BN = 32
  int slot = blockIdx.x >> 5;
  if (slot >= nmt[0]) return;
  int tl = tiles[slot];
  int e = tl >> 16, mtile = tl & 0xffff;
  int row0 = offsets[e] + mtile * BM;
  int rowEnd = offsets[e + 1];
  int col0 = ntid * BN;

  __shared__ __align__(16) char smem[32768];
  unsigned short* As = (unsigned short*)smem;              // 128x64 bf16
  unsigned short* B1s = (unsigned short*)(smem + 16384);   // 64x64
  unsigned short* B3s = (unsigned short*)(smem + 24576);   // 64x64

  int tid = threadIdx.x, lane = tid & 63, w = tid >> 6;
  int wr = w >> 1, wc = w & 1;

  f32x4 acc1[4][2], acc3[4][2];
#pragma unroll
  for (int i = 0; i < 4; i++)
#pragma unroll
    for (int j = 0; j < 2; j++)
#pragma unroll
      for (int k = 0; k < 4; k++) { acc1[i][j][k] = 0.f; acc3[i][j][k] = 0.f; }

  const unsigned short* Ag = Xg + (size_t)row0 * DIM;
  const float* W1e = W1 + ((size_t)e * HID + col0) * DIM;
  const float* W3e = W3 + ((size_t)e * HID + col0) * DIM;

  for (int kt = 0; kt < DIM / BK; kt++) {
#pragma unroll
    for (int it = 0; it < 4; it++) {
      int rl = it * 32 + w * 8 + (lane >> 3);
      int cb = (lane & 7) * 8;
      gload_lds16(Ag + (size_t)rl * DIM + kt * BK + cb, As + (it * 32 + w * 8) * BK);
    }
#pragma unroll
    for (int it = 0; it < 4; it++) {
      int rl = it * 16 + (tid >> 4);
      int cs = (tid & 15) * 4;
      float4 f1 = *(const float4*)(W1e + (size_t)rl * DIM + kt * BK + cs);
      float4 f3 = *(const float4*)(W3e + (size_t)rl * DIM + kt * BK + cs);
      ushort4 h1, h3;
      h1.x = f2bf(f1.x); h1.y = f2bf(f1.y); h1.z = f2bf(f1.z); h1.w = f2bf(f1.w);
      h3.x = f2bf(f3.x); h3.y = f2bf(f3.y); h3.z = f2bf(f3.z); h3.w = f2bf(f3.w);
      *(ushort4*)(B1s + rl * BK + cs) = h1;
      *(ushort4*)(B3s + rl * BK + cs) = h3;
    }
    __syncthreads();
#pragma unroll
    for (int kk = 0; kk < 2; kk++) {
      bf16x8 a[4];
#pragma unroll
      for (int mm = 0; mm < 4; mm++)
        a[mm] = *(const bf16x8*)(As + (wr * 64 + mm * 16 + (lane & 15)) * BK + kk * 32 + (lane >> 4) * 8);
#pragma unroll
      for (int nn = 0; nn < 2; nn++) {
        bf16x8 bv1 = *(const bf16x8*)(B1s + (wc * 32 + nn * 16 + (lane & 15)) * BK + kk * 32 + (lane >> 4) * 8);
        bf16x8 bv3 = *(const bf16x8*)(B3s + (wc * 32 + nn * 16 + (lane & 15)) * BK + kk * 32 + (lane >> 4) * 8);
#pragma unroll
        for (int mm = 0; mm < 4; mm++) {
          acc1[mm][nn] = __builtin_amdgcn_mfma_f32_16x16x32_bf16(a[mm], bv1, acc1[mm][nn], 0, 0, 0);
          acc3[mm][nn] = __builtin_amdgcn_mfma_f32_16x16x32_bf16(a[mm], bv3, acc3[mm][nn], 0, 0, 0);
        }
      }
    }
    __syncthreads();
  }

  // epilogue: bias + rank-16 lora + silu-gate, store bf16 g
  float* sT1 = (float*)smem;            // 128x17
  float* sT3 = sT1 + 128 * 17;
  float* sC1 = sT3 + 128 * 17;          // 64x17
  float* sC3 = sC1 + 64 * 17;
  float* sb1 = sC3 + 64 * 17;           // 64
  float* sb3 = sb1 + 64;
  for (int i = tid; i < 128 * 16; i += 256) {
    int rr = i >> 4, jj = i & 15;
    sT1[rr * 17 + jj] = t1g[(size_t)(row0 + rr) * LR + jj];
    sT3[rr * 17 + jj] = t3g[(size_t)(row0 + rr) * LR + jj];
  }
  for (int i = tid; i < 64 * 16; i += 256) {
    int rr = i >> 4, jj = i & 15;
    sC1[rr * 17 + jj] = B1l[((size_t)e * HID + col0 + rr) * LR + jj];
    sC3[rr * 17 + jj] = B3l[((size_t)e * HID + col0 + rr) * LR + jj];
  }
  if (tid < 64) {
    sb1[tid] = b1[e * HID + col0 + tid];
    sb3[tid] = b3[e * HID + col0 + tid];
  }
  __syncthreads();
#pragma unroll
  for (int mm = 0; mm < 4; mm++)
#pragma unroll
    for (int nn = 0; nn < 2; nn++) {
      int cl = wc * 32 + nn * 16 + (lane & 15);
      float bias1 = sb1[cl], bias3 = sb3[cl];
#pragma unroll
      for (int j = 0; j < 4; j++) {
        int rl = wr * 64 + mm * 16 + (lane >> 4) * 4 + j;
        float v1 = acc1[mm][nn][j] + bias1;
        float v3 = acc3[mm][nn][j] + bias3;
#pragma unroll
        for (int jj = 0; jj < 16; jj++) {
          v1 += sT1[rl * 17 + jj] * sC1[cl * 17 + jj];
          v3 += sT3[rl * 17 + jj] * sC3[cl * 17 + jj];
        }
        float gg = v1 * v3 / (1.f + __expf(-v1));
        int r = row0 + rl;
        if (r < rowEnd) g[(size_t)r * HID + col0 + cl] = f2bf(gg);
      }
    }
}

// ---------------- GEMM2: ye = g W2^T + lora + b2 ---------------------------
__global__ __launch_bounds__(256) void gemm2_kernel(
    const unsigned short* __restrict__ gb,
    const float* __restrict__ W2, const float* __restrict__ b2,
    const float* __restrict__ B2l, const float* __restrict__ t2g,
    const int* __restrict__ offsets, const int* __restrict__ nmt,
    const int* __restrict__ tiles,
    float* __restrict__ ye) {
  int ntid = blockIdx.x & 15;   // DIM/BN = 16
  int slot = blockIdx.x >> 4;
  if (slot >= nmt[0]) return;
  int tl = tiles[slot];
  int e = tl >> 16, mtile = tl & 0xffff;
  int row0 = offsets[e] + mtile * BM;
  int rowEnd = offsets[e + 1];
  int col0 = ntid * BN;

  __shared__ __align__(16) char smem[24576];
  unsigned short* As = (unsigned short*)smem;            // 128x64
  unsigned short* Bs = (unsigned short*)(smem + 16384);  // 64x64

  int tid = threadIdx.x, lane = tid & 63, w = tid >> 6;
  int wr = w >> 1, wc = w & 1;

  f32x4 acc[4][2];
#pragma unroll
  for (int i = 0; i < 4; i++)
#pragma unroll
    for (int j = 0; j < 2; j++)
#pragma unroll
      for (int k = 0; k < 4; k++) acc[i][j][k] = 0.f;

  const unsigned short* Ag = gb + (size_t)row0 * HID;
  const float* W2e = W2 + ((size_t)e * DIM + col0) * HID;

  for (int kt = 0; kt < HID / BK; kt++) {
#pragma unroll
    for (int it = 0; it < 4; it++) {
      int rl = it * 32 + w * 8 + (lane >> 3);
      int cb = (lane & 7) * 8;
      gload_lds16(Ag + (size_t)rl * HID + kt * BK + cb, As + (it * 32 + w * 8) * BK);
    }
#pragma unroll
    for (int it = 0; it < 4; it++) {
      int rl = it * 16 + (tid >> 4);
      int cs = (tid & 15) * 4;
      float4 f = *(const float4*)(W2e + (size_t)rl * HID + kt * BK + cs);
      ushort4 h;
      h.x = f2bf(f.x); h.y = f2bf(f.y); h.z = f2bf(f.z); h.w = f2bf(f.w);
      *(ushort4*)(Bs + rl * BK + cs) = h;
    }
    __syncthreads();
#pragma unroll
    for (int kk = 0; kk < 2; kk++) {
      bf16x8 a[4];
#pragma unroll
      for (int mm = 0; mm < 4; mm++)
        a[mm] = *(const bf16x8*)(As + (wr * 64 + mm * 16 + (lane & 15)) * BK + kk * 32 + (lane >> 4) * 8);
#pragma unroll
      for (int nn = 0; nn < 2; nn++) {
        bf16x8 bv = *(const bf16x8*)(Bs + (wc * 32 + nn * 16 + (lane & 15)) * BK + kk * 32 + (lane >> 4) * 8);
#pragma unroll
        for (int mm = 0; mm < 4; mm++)
          acc[mm][nn] = __builtin_amdgcn_mfma_f32_16x16x32_bf16(a[mm], bv, acc[mm][nn], 0, 0, 0);
      }
    }
    __syncthreads();
  }

  float* sT2 = (float*)smem;        // 128x17
  float* sC2 = sT2 + 128 * 17;      // 64x17
  float* sb2 = sC2 + 64 * 17;       // 64
  for (int i = tid; i < 128 * 16; i += 256) {
    int rr = i >> 4, jj = i & 15;
    sT2[rr * 17 + jj] = t2g[(size_t)(row0 + rr) * LR + jj];
  }
  for (int i = tid; i < 64 * 16; i += 256) {
    int rr = i >> 4, jj = i & 15;
    sC2[rr * 17 + jj] = B2l[((size_t)e * DIM + col0 + rr) * LR + jj];
  }
  if (tid < 64) sb2[tid] = b2[e * DIM + col0 + tid];
  __syncthreads();
#pragma unroll
  for (int mm = 0; mm < 4; mm++)
#pragma unroll
    for (int nn = 0; nn < 2; nn++) {
      int cl = wc * 32 + nn * 16 + (lane & 15);
      float bias = sb2[cl];
#pragma unroll
      for (int j = 0; j < 4; j++) {
        int rl = wr * 64 + mm * 16 + (lane >> 4) * 4 + j;
        float v = acc[mm][nn][j] + bias;
#pragma unroll
        for (int jj = 0; jj < 16; jj++) v += sT2[rl * 17 + jj] * sC2[cl * 17 + jj];
        int r = row0 + rl;
        if (r < rowEnd) ye[(size_t)r * DIM + col0 + cl] = v;
      }
    }
}

// ---------------- combine: y[t] = w0*ye[r0] + w1*ye[r1] (fp32 out!) --------
__global__ void combine_kernel(const float* __restrict__ ye, const int* __restrict__ pos,
                               const float* __restrict__ topk_gate,
                               float* __restrict__ out) {
  int t = blockIdx.x, tid = threadIdx.x;
  int r0 = pos[2 * t], r1 = pos[2 * t + 1];
  float w0 = topk_gate[2 * t], w1 = topk_gate[2 * t + 1];
  float4 a = ((const float4*)(ye + (size_t)r0 * DIM))[tid];
  float4 b = ((const float4*)(ye + (size_t)r1 * DIM))[tid];
  float4 o;
  o.x = w0 * a.x + w1 * b.x;
  o.y = w0 * a.y + w1 * b.y;
  o.z = w0 * a.z + w1 * b.z;
  o.w = w0 * a.w + w1 * b.w;
  ((float4*)(out + (size_t)t * DIM))[tid] = o;
}

extern "C" void kernel_launch(void* const* d_in, const int* in_sizes, int n_in,
                              void* d_out, int out_size, void* d_ws, size_t ws_size,
                              hipStream_t stream) {
  (void)in_sizes; (void)n_in; (void)out_size; (void)ws_size;
  const float* x  = (const float*)d_in[0];
  const float* Wg = (const float*)d_in[1];
  const float* W1 = (const float*)d_in[2];
  const float* b1 = (const float*)d_in[3];
  const float* A1 = (const float*)d_in[4];
  const float* B1 = (const float*)d_in[5];
  const float* W2 = (const float*)d_in[6];
  const float* b2 = (const float*)d_in[7];
  const float* A2 = (const float*)d_in[8];
  const float* B2 = (const float*)d_in[9];
  const float* W3 = (const float*)d_in[10];
  const float* b3 = (const float*)d_in[11];
  const float* A3 = (const float*)d_in[12];
  const float* B3 = (const float*)d_in[13];
  float* out = (float*)d_out;

  char* ws = (char*)d_ws;
  int* counts   = (int*)ws;        // 8
  int* cursors  = counts + 8;      // 8
  int* offsets  = cursors + 8;     // 9
  int* nmt      = offsets + 9;     // 1
  int* tiles    = nmt + 1;         // 40
  int* topk_idx = (int*)(ws + 512);
  float* topk_gate = (float*)(ws + 512 + 16384);
  int* perm   = (int*)(ws + 512 + 2 * 16384);
  int* rowexp = (int*)(ws + 512 + 3 * 16384);
  int* pos    = (int*)(ws + 512 + 4 * 16384);
  size_t off = 82432;  // 512 + 5*16384, 256-aligned
  unsigned short* Xg = (unsigned short*)(ws + off); off += (size_t)ROWS_PAD * DIM * 2;
  unsigned short* gb = (unsigned short*)(ws + off); off += (size_t)ROWS_PAD * HID * 2;
  float* t1g = (float*)(ws + off); off += (size_t)ROWS_PAD * LR * 4;
  float* t3g = (float*)(ws + off); off += (size_t)ROWS_PAD * LR * 4;
  float* t2g = (float*)(ws + off); off += (size_t)ROWS_PAD * LR * 4;
  float* ye  = (float*)(ws + off); off += (size_t)NROWS * DIM * 4;

  hipMemsetAsync(d_ws, 0, 512, stream);
  routing_kernel<<<T_TOK / 4, 256, 0, stream>>>(x, Wg, counts, topk_idx, topk_gate);
  scan_kernel<<<1, 64, 0, stream>>>(counts, offsets, nmt, tiles);
  scatter_kernel<<<NROWS / 256, 256, 0, stream>>>(topk_idx, offsets, cursors, perm, rowexp, pos);
  gather_lora13_kernel<<<NROWS, 256, 0, stream>>>(x, A1, A3, perm, rowexp, Xg, t1g, t3g);
  gemm1_dual<<<MAX_MT * (HID / BN), 256, 0, stream>>>(Xg, W1, W3, b1, b3, B1, B3, t1g, t3g,
                                                      offsets, nmt, tiles, gb);
  lora2_kernel<<<NROWS, 256, 0, stream>>>(gb, A2, rowexp, t2g);
  gemm2_kernel<<<MAX_MT * (DIM / BN), 256, 0, stream>>>(gb, W2, b2, B2, t2g,
                                                        offsets, nmt, tiles, ye);
  combine_kernel<<<T_TOK, 256, 0, stream>>>(ye, pos, topk_gate, out);
}

// Round 4
// 599.943 us; speedup vs baseline: 1.1502x; 1.1502x over previous
//
#include <hip/hip_runtime.h>

#define DIM 1024
#define HID 2048
#define NE 8
#define LR 16
#define T_TOK 2048
#define NROWS 4096
#define BM 128
#define BN 64
#define BK 64
#define MAX_MT 40
#define ROWS_PAD (NROWS + BM)
#define WELEMS (NE * HID * DIM)   // 16.78M elems per weight tensor

typedef __attribute__((ext_vector_type(8))) short bf16x8;
typedef __attribute__((ext_vector_type(4))) float f32x4;

__device__ __forceinline__ unsigned short f2bf(float f) {
  unsigned u = __builtin_bit_cast(unsigned, f);
  u += 0x7FFFu + ((u >> 16) & 1u);
  return (unsigned short)(u >> 16);
}

__device__ __forceinline__ void gload_lds16(const void* g, void* l) {
  __builtin_amdgcn_global_load_lds(
      (const __attribute__((address_space(1))) unsigned int*)g,
      (__attribute__((address_space(3))) unsigned int*)l, 16, 0, 0);
}

// ---------------- weight fp32 -> bf16 convert ------------------------------
__global__ void wconv_kernel(const float* __restrict__ f, unsigned short* __restrict__ o, int n) {
  for (int i = (blockIdx.x * 256 + threadIdx.x) * 8; i < n; i += gridDim.x * 256 * 8) {
    float4 a = *(const float4*)(f + i);
    float4 b = *(const float4*)(f + i + 4);
    ushort4 h0, h1;
    h0.x = f2bf(a.x); h0.y = f2bf(a.y); h0.z = f2bf(a.z); h0.w = f2bf(a.w);
    h1.x = f2bf(b.x); h1.y = f2bf(b.y); h1.z = f2bf(b.z); h1.w = f2bf(b.w);
    *(ushort4*)(o + i) = h0;
    *(ushort4*)(o + i + 4) = h1;
  }
}

// ---------------- routing: logits -> top2 -> gates -------------------------
__global__ void routing_kernel(const float* __restrict__ x, const float* __restrict__ Wg,
                               int* __restrict__ counts, int* __restrict__ topk_idx,
                               float* __restrict__ topk_gate) {
  int t = blockIdx.x * 4 + (threadIdx.x >> 6);
  int lane = threadIdx.x & 63;
  const float* xr = x + (size_t)t * DIM;
  float xa[16];
#pragma unroll
  for (int i = 0; i < 16; i++) xa[i] = xr[lane + 64 * i];
  float lg[NE];
#pragma unroll
  for (int e = 0; e < NE; e++) {
    const float* wr_ = Wg + e * DIM;
    float s = 0.f;
#pragma unroll
    for (int i = 0; i < 16; i++) s += xa[i] * wr_[lane + 64 * i];
#pragma unroll
    for (int off = 32; off > 0; off >>= 1) s += __shfl_xor(s, off);
    lg[e] = s;
  }
  if (lane == 0) {
    int i0 = 0;
#pragma unroll
    for (int e = 1; e < NE; e++) if (lg[e] > lg[i0]) i0 = e;
    int i1 = (i0 == 0) ? 1 : 0;
#pragma unroll
    for (int e = 0; e < NE; e++) if (e != i0 && lg[e] > lg[i1]) i1 = e;
    float e1 = __expf(lg[i1] - lg[i0]);
    float inv = 1.f / (1.f + e1);
    topk_idx[2 * t] = i0;
    topk_idx[2 * t + 1] = i1;
    topk_gate[2 * t] = inv;
    topk_gate[2 * t + 1] = e1 * inv;
    atomicAdd(&counts[i0], 1);
    atomicAdd(&counts[i1], 1);
  }
}

// ---------------- scan: offsets + tile schedule ----------------------------
__global__ void scan_kernel(const int* __restrict__ counts, int* __restrict__ offsets,
                            int* __restrict__ nmt, int* __restrict__ tiles) {
  if (threadIdx.x == 0) {
    int off = 0, nt = 0;
    for (int e = 0; e < NE; e++) {
      offsets[e] = off;
      int c = counts[e];
      for (int mm = 0; mm * BM < c; mm++) tiles[nt++] = (e << 16) | mm;
      off += c;
    }
    offsets[NE] = off;
    nmt[0] = nt;
  }
}

// ---------------- scatter: (t,slot) -> compact row -------------------------
__global__ void scatter_kernel(const int* __restrict__ topk_idx,
                               const int* __restrict__ offsets, int* __restrict__ cursors,
                               int* __restrict__ perm, int* __restrict__ rowexp,
                               int* __restrict__ pos) {
  int i = blockIdx.x * 256 + threadIdx.x;
  int e = topk_idx[i];
  int r = offsets[e] + atomicAdd(&cursors[e], 1);
  perm[r] = i >> 1;
  rowexp[r] = e;
  pos[i] = r;
}

// ---------------- gather x rows (bf16) + t1=xA1^T, t3=xA3^T ----------------
__global__ void gather_lora13_kernel(const float* __restrict__ x,
                                     const float* __restrict__ A1, const float* __restrict__ A3,
                                     const int* __restrict__ perm, const int* __restrict__ rowexp,
                                     unsigned short* __restrict__ Xg,
                                     float* __restrict__ t1g, float* __restrict__ t3g) {
  __shared__ float xs[DIM];
  int r = blockIdx.x;
  int t = perm[r], e = rowexp[r];
  int tid = threadIdx.x;
  float4 v = ((const float4*)(x + (size_t)t * DIM))[tid];
  ((float4*)xs)[tid] = v;
  ushort4 hv;
  hv.x = f2bf(v.x); hv.y = f2bf(v.y); hv.z = f2bf(v.z); hv.w = f2bf(v.w);
  ((ushort4*)(Xg + (size_t)r * DIM))[tid] = hv;
  __syncthreads();
  int w = tid >> 6, lane = tid & 63;
  const float* A = ((w < 2) ? A1 : A3) + (size_t)e * LR * DIM + (size_t)((w & 1) * 8) * DIM;
  float* tout = ((w < 2) ? t1g : t3g) + (size_t)r * LR + (w & 1) * 8;
  float acc[8];
#pragma unroll
  for (int j = 0; j < 8; j++) acc[j] = 0.f;
  for (int i = 0; i < 16; i++) {
    float xv = xs[lane + 64 * i];
#pragma unroll
    for (int j = 0; j < 8; j++) acc[j] += xv * A[(size_t)j * DIM + lane + 64 * i];
  }
#pragma unroll
  for (int j = 0; j < 8; j++) {
    float s = acc[j];
#pragma unroll
    for (int off = 32; off > 0; off >>= 1) s += __shfl_xor(s, off);
    if (lane == 0) tout[j] = s;
  }
}

// ---------------- t2 = g A2^T ----------------------------------------------
__global__ void lora2_kernel(const unsigned short* __restrict__ gb,
                             const float* __restrict__ A2, const int* __restrict__ rowexp,
                             float* __restrict__ t2g) {
  __shared__ float gs[HID];
  int r = blockIdx.x, tid = threadIdx.x;
  int e = rowexp[r];
  uint4 raw = ((const uint4*)(gb + (size_t)r * HID))[tid];
  unsigned u[4] = {raw.x, raw.y, raw.z, raw.w};
#pragma unroll
  for (int k = 0; k < 4; k++) {
    gs[tid * 8 + 2 * k] = __builtin_bit_cast(float, u[k] << 16);
    gs[tid * 8 + 2 * k + 1] = __builtin_bit_cast(float, u[k] & 0xffff0000u);
  }
  __syncthreads();
  int w = tid >> 6, lane = tid & 63;
  const float* A = A2 + (size_t)e * LR * HID + (size_t)(w * 4) * HID;
  float acc[4];
#pragma unroll
  for (int j = 0; j < 4; j++) acc[j] = 0.f;
  for (int i = 0; i < HID / 64; i++) {
    float xv = gs[lane + 64 * i];
#pragma unroll
    for (int j = 0; j < 4; j++) acc[j] += xv * A[(size_t)j * HID + lane + 64 * i];
  }
#pragma unroll
  for (int j = 0; j < 4; j++) {
    float s = acc[j];
#pragma unroll
    for (int off = 32; off > 0; off >>= 1) s += __shfl_xor(s, off);
    if (lane == 0) t2g[(size_t)r * LR + w * 4 + j] = s;
  }
}

// ---------------- GEMM1: g = silu(Xg W1^T + lora + b1) * (Xg W3^T + lora + b3)
// 2-phase double-buffered, all-bf16 staging via global_load_lds, XOR-swizzled LDS.
__global__ __launch_bounds__(256) void gemm1_dual(
    const unsigned short* __restrict__ Xg,
    const unsigned short* __restrict__ W1b, const unsigned short* __restrict__ W3b,
    const float* __restrict__ b1, const float* __restrict__ b3,
    const float* __restrict__ B1l, const float* __restrict__ B3l,
    const float* __restrict__ t1g, const float* __restrict__ t3g,
    const int* __restrict__ offsets, const int* __restrict__ nmt,
    const int* __restrict__ tiles,
    unsigned short* __restrict__ g) {
  int ntid = blockIdx.x & 31;   // HID/BN = 32
  int slot = blockIdx.x >> 5;
  if (slot >= nmt[0]) return;
  int tl = tiles[slot];
  int e = tl >> 16, mtile = tl & 0xffff;
  int row0 = offsets[e] + mtile * BM;
  int rowEnd = offsets[e + 1];
  int col0 = ntid * BN;

  __shared__ __align__(16) char smem[65536];  // 2 x (16K A + 8K B1 + 8K B3)

  int tid = threadIdx.x, lane = tid & 63, w = tid >> 6;
  int wr = w >> 1, wc = w & 1;
  int srow = lane >> 3;                         // 0..7
  int sperm = ((lane & 7) ^ srow) * 8;          // pre-swizzled global col (elems)
  int lxor = (lane & 7) << 3;                   // read-side XOR (elems)

  f32x4 acc1[4][2], acc3[4][2];
#pragma unroll
  for (int i = 0; i < 4; i++)
#pragma unroll
    for (int j = 0; j < 2; j++)
#pragma unroll
      for (int k = 0; k < 4; k++) { acc1[i][j][k] = 0.f; acc3[i][j][k] = 0.f; }

  const unsigned short* Ag = Xg + (size_t)row0 * DIM;
  const unsigned short* W1e = W1b + ((size_t)e * HID + col0) * DIM;
  const unsigned short* W3e = W3b + ((size_t)e * HID + col0) * DIM;

#define STAGE1(buf, kt) { \
    char* base_ = smem + (buf) * 32768; \
    unsigned short* As_ = (unsigned short*)base_; \
    unsigned short* B1s_ = (unsigned short*)(base_ + 16384); \
    unsigned short* B3s_ = (unsigned short*)(base_ + 24576); \
    int kc_ = (kt) * BK + sperm; \
    _Pragma("unroll") \
    for (int it = 0; it < 4; it++) \
      gload_lds16(Ag + (size_t)(it * 32 + w * 8 + srow) * DIM + kc_, As_ + (it * 32 + w * 8) * BK); \
    _Pragma("unroll") \
    for (int it = 0; it < 2; it++) { \
      gload_lds16(W1e + (size_t)(it * 32 + w * 8 + srow) * DIM + kc_, B1s_ + (it * 32 + w * 8) * BK); \
      gload_lds16(W3e + (size_t)(it * 32 + w * 8 + srow) * DIM + kc_, B3s_ + (it * 32 + w * 8) * BK); \
    } }

  STAGE1(0, 0);
  __syncthreads();
  int cur = 0;
  const int NT1 = DIM / BK;  // 16
  for (int kt = 0; kt < NT1; kt++) {
    if (kt + 1 < NT1) STAGE1(cur ^ 1, kt + 1);
    {
      char* base_ = smem + cur * 32768;
      const unsigned short* As_ = (const unsigned short*)base_;
      const unsigned short* B1s_ = (const unsigned short*)(base_ + 16384);
      const unsigned short* B3s_ = (const unsigned short*)(base_ + 24576);
#pragma unroll
      for (int kk = 0; kk < 2; kk++) {
        int kx = (kk * 32 + (lane >> 4) * 8) ^ lxor;
        bf16x8 a[4];
#pragma unroll
        for (int mm = 0; mm < 4; mm++)
          a[mm] = *(const bf16x8*)(As_ + (wr * 64 + mm * 16 + (lane & 15)) * BK + kx);
#pragma unroll
        for (int nn = 0; nn < 2; nn++) {
          bf16x8 bv1 = *(const bf16x8*)(B1s_ + (wc * 32 + nn * 16 + (lane & 15)) * BK + kx);
          bf16x8 bv3 = *(const bf16x8*)(B3s_ + (wc * 32 + nn * 16 + (lane & 15)) * BK + kx);
#pragma unroll
          for (int mm = 0; mm < 4; mm++) {
            acc1[mm][nn] = __builtin_amdgcn_mfma_f32_16x16x32_bf16(a[mm], bv1, acc1[mm][nn], 0, 0, 0);
            acc3[mm][nn] = __builtin_amdgcn_mfma_f32_16x16x32_bf16(a[mm], bv3, acc3[mm][nn], 0, 0, 0);
          }
        }
      }
    }
    __syncthreads();
    cur ^= 1;
  }

  // epilogue: bias + rank-16 lora + silu-gate, store bf16 g
  float* sT1 = (float*)smem;            // 128x17
  float* sT3 = sT1 + 128 * 17;
  float* sC1 = sT3 + 128 * 17;          // 64x17
  float* sC3 = sC1 + 64 * 17;
  float* sb1 = sC3 + 64 * 17;           // 64
  float* sb3 = sb1 + 64;
  for (int i = tid; i < 128 * 16; i += 256) {
    int rr = i >> 4, jj = i & 15;
    sT1[rr * 17 + jj] = t1g[(size_t)(row0 + rr) * LR + jj];
    sT3[rr * 17 + jj] = t3g[(size_t)(row0 + rr) * LR + jj];
  }
  for (int i = tid; i < 64 * 16; i += 256) {
    int rr = i >> 4, jj = i & 15;
    sC1[rr * 17 + jj] = B1l[((size_t)e * HID + col0 + rr) * LR + jj];
    sC3[rr * 17 + jj] = B3l[((size_t)e * HID + col0 + rr) * LR + jj];
  }
  if (tid < 64) {
    sb1[tid] = b1[e * HID + col0 + tid];
    sb3[tid] = b3[e * HID + col0 + tid];
  }
  __syncthreads();
#pragma unroll
  for (int mm = 0; mm < 4; mm++)
#pragma unroll
    for (int nn = 0; nn < 2; nn++) {
      int cl = wc * 32 + nn * 16 + (lane & 15);
      float bias1 = sb1[cl], bias3 = sb3[cl];
#pragma unroll
      for (int j = 0; j < 4; j++) {
        int rl = wr * 64 + mm * 16 + (lane >> 4) * 4 + j;
        float v1 = acc1[mm][nn][j] + bias1;
        float v3 = acc3[mm][nn][j] + bias3;
#pragma unroll
        for (int jj = 0; jj < 16; jj++) {
          v1 += sT1[rl * 17 + jj] * sC1[cl * 17 + jj];
          v3 += sT3[rl * 17 + jj] * sC3[cl * 17 + jj];
        }
        float gg = v1 * v3 / (1.f + __expf(-v1));
        int r = row0 + rl;
        if (r < rowEnd) g[(size_t)r * HID + col0 + cl] = f2bf(gg);
      }
    }
}

// ---------------- GEMM2: ye = g W2^T + lora + b2 ---------------------------
__global__ __launch_bounds__(256) void gemm2_kernel(
    const unsigned short* __restrict__ gb,
    const unsigned short* __restrict__ W2b, const float* __restrict__ b2,
    const float* __restrict__ B2l, const float* __restrict__ t2g,
    const int* __restrict__ offsets, const int* __restrict__ nmt,
    const int* __restrict__ tiles,
    float* __restrict__ ye) {
  int ntid = blockIdx.x & 15;   // DIM/BN = 16
  int slot = blockIdx.x >> 4;
  if (slot >= nmt[0]) return;
  int tl = tiles[slot];
  int e = tl >> 16, mtile = tl & 0xffff;
  int row0 = offsets[e] + mtile * BM;
  int rowEnd = offsets[e + 1];
  int col0 = ntid * BN;

  __shared__ __align__(16) char smem[49152];  // 2 x (16K A + 8K B)

  int tid = threadIdx.x, lane = tid & 63, w = tid >> 6;
  int wr = w >> 1, wc = w & 1;
  int srow = lane >> 3;
  int sperm = ((lane & 7) ^ srow) * 8;
  int lxor = (lane & 7) << 3;

  f32x4 acc[4][2];
#pragma unroll
  for (int i = 0; i < 4; i++)
#pragma unroll
    for (int j = 0; j < 2; j++)
#pragma unroll
      for (int k = 0; k < 4; k++) acc[i][j][k] = 0.f;

  const unsigned short* Ag = gb + (size_t)row0 * HID;
  const unsigned short* W2e = W2b + ((size_t)e * DIM + col0) * HID;

#define STAGE2(buf, kt) { \
    char* base_ = smem + (buf) * 24576; \
    unsigned short* As_ = (unsigned short*)base_; \
    unsigned short* Bs_ = (unsigned short*)(base_ + 16384); \
    int kc_ = (kt) * BK + sperm; \
    _Pragma("unroll") \
    for (int it = 0; it < 4; it++) \
      gload_lds16(Ag + (size_t)(it * 32 + w * 8 + srow) * HID + kc_, As_ + (it * 32 + w * 8) * BK); \
    _Pragma("unroll") \
    for (int it = 0; it < 2; it++) \
      gload_lds16(W2e + (size_t)(it * 32 + w * 8 + srow) * HID + kc_, Bs_ + (it * 32 + w * 8) * BK); \
    }

  STAGE2(0, 0);
  __syncthreads();
  int cur = 0;
  const int NT2 = HID / BK;  // 32
  for (int kt = 0; kt < NT2; kt++) {
    if (kt + 1 < NT2) STAGE2(cur ^ 1, kt + 1);
    {
      char* base_ = smem + cur * 24576;
      const unsigned short* As_ = (const unsigned short*)base_;
      const unsigned short* Bs_ = (const unsigned short*)(base_ + 16384);
#pragma unroll
      for (int kk = 0; kk < 2; kk++) {
        int kx = (kk * 32 + (lane >> 4) * 8) ^ lxor;
        bf16x8 a[4];
#pragma unroll
        for (int mm = 0; mm < 4; mm++)
          a[mm] = *(const bf16x8*)(As_ + (wr * 64 + mm * 16 + (lane & 15)) * BK + kx);
#pragma unroll
        for (int nn = 0; nn < 2; nn++) {
          bf16x8 bv = *(const bf16x8*)(Bs_ + (wc * 32 + nn * 16 + (lane & 15)) * BK + kx);
#pragma unroll
          for (int mm = 0; mm < 4; mm++)
            acc[mm][nn] = __builtin_amdgcn_mfma_f32_16x16x32_bf16(a[mm], bv, acc[mm][nn], 0, 0, 0);
        }
      }
    }
    __syncthreads();
    cur ^= 1;
  }

  float* sT2 = (float*)smem;        // 128x17
  float* sC2 = sT2 + 128 * 17;      // 64x17
  float* sb2 = sC2 + 64 * 17;       // 64
  for (int i = tid; i < 128 * 16; i += 256) {
    int rr = i >> 4, jj = i & 15;
    sT2[rr * 17 + jj] = t2g[(size_t)(row0 + rr) * LR + jj];
  }
  for (int i = tid; i < 64 * 16; i += 256) {
    int rr = i >> 4, jj = i & 15;
    sC2[rr * 17 + jj] = B2l[((size_t)e * DIM + col0 + rr) * LR + jj];
  }
  if (tid < 64) sb2[tid] = b2[e * DIM + col0 + tid];
  __syncthreads();
#pragma unroll
  for (int mm = 0; mm < 4; mm++)
#pragma unroll
    for (int nn = 0; nn < 2; nn++) {
      int cl = wc * 32 + nn * 16 + (lane & 15);
      float bias = sb2[cl];
#pragma unroll
      for (int j = 0; j < 4; j++) {
        int rl = wr * 64 + mm * 16 + (lane >> 4) * 4 + j;
        float v = acc[mm][nn][j] + bias;
#pragma unroll
        for (int jj = 0; jj < 16; jj++) v += sT2[rl * 17 + jj] * sC2[cl * 17 + jj];
        int r = row0 + rl;
        if (r < rowEnd) ye[(size_t)r * DIM + col0 + cl] = v;
      }
    }
}

// ---------------- combine: y[t] = w0*ye[r0] + w1*ye[r1] (fp32 out) ---------
__global__ void combine_kernel(const float* __restrict__ ye, const int* __restrict__ pos,
                               const float* __restrict__ topk_gate,
                               float* __restrict__ out) {
  int t = blockIdx.x, tid = threadIdx.x;
  int r0 = pos[2 * t], r1 = pos[2 * t + 1];
  float w0 = topk_gate[2 * t], w1 = topk_gate[2 * t + 1];
  float4 a = ((const float4*)(ye + (size_t)r0 * DIM))[tid];
  float4 b = ((const float4*)(ye + (size_t)r1 * DIM))[tid];
  float4 o;
  o.x = w0 * a.x + w1 * b.x;
  o.y = w0 * a.y + w1 * b.y;
  o.z = w0 * a.z + w1 * b.z;
  o.w = w0 * a.w + w1 * b.w;
  ((float4*)(out + (size_t)t * DIM))[tid] = o;
}

extern "C" void kernel_launch(void* const* d_in, const int* in_sizes, int n_in,
                              void* d_out, int out_size, void* d_ws, size_t ws_size,
                              hipStream_t stream) {
  (void)in_sizes; (void)n_in; (void)out_size; (void)ws_size;
  const float* x  = (const float*)d_in[0];
  const float* Wg = (const float*)d_in[1];
  const float* W1 = (const float*)d_in[2];
  const float* b1 = (const float*)d_in[3];
  const float* A1 = (const float*)d_in[4];
  const float* B1 = (const float*)d_in[5];
  const float* W2 = (const float*)d_in[6];
  const float* b2 = (const float*)d_in[7];
  const float* A2 = (const float*)d_in[8];
  const float* B2 = (const float*)d_in[9];
  const float* W3 = (const float*)d_in[10];
  const float* b3 = (const float*)d_in[11];
  const float* A3 = (const float*)d_in[12];
  const float* B3 = (const float*)d_in[13];
  float* out = (float*)d_out;

  char* ws = (char*)d_ws;
  int* counts   = (int*)ws;        // 8
  int* cursors  = counts + 8;      // 8
  int* offsets  = cursors + 8;     // 9
  int* nmt      = offsets + 9;     // 1
  int* tiles    = nmt + 1;         // 40
  int* topk_idx = (int*)(ws + 512);
  float* topk_gate = (float*)(ws + 512 + 16384);
  int* perm   = (int*)(ws + 512 + 2 * 16384);
  int* rowexp = (int*)(ws + 512 + 3 * 16384);
  int* pos    = (int*)(ws + 512 + 4 * 16384);
  size_t off = 82432;  // 512 + 5*16384, 256-aligned
  unsigned short* Xg = (unsigned short*)(ws + off); off += (size_t)ROWS_PAD * DIM * 2;
  unsigned short* gb = (unsigned short*)(ws + off); off += (size_t)ROWS_PAD * HID * 2;
  float* t1g = (float*)(ws + off); off += (size_t)ROWS_PAD * LR * 4;
  float* t3g = (float*)(ws + off); off += (size_t)ROWS_PAD * LR * 4;
  float* t2g = (float*)(ws + off); off += (size_t)ROWS_PAD * LR * 4;
  float* ye  = (float*)(ws + off); off += (size_t)NROWS * DIM * 4;
  unsigned short* W1b = (unsigned short*)(ws + off); off += (size_t)WELEMS * 2;
  unsigned short* W3b = (unsigned short*)(ws + off); off += (size_t)WELEMS * 2;
  unsigned short* W2b = (unsigned short*)(ws + off); off += (size_t)WELEMS * 2;

  hipMemsetAsync(d_ws, 0, 512, stream);
  wconv_kernel<<<4096, 256, 0, stream>>>(W1, W1b, WELEMS);
  wconv_kernel<<<4096, 256, 0, stream>>>(W3, W3b, WELEMS);
  wconv_kernel<<<4096, 256, 0, stream>>>(W2, W2b, WELEMS);
  routing_kernel<<<T_TOK / 4, 256, 0, stream>>>(x, Wg, counts, topk_idx, topk_gate);
  scan_kernel<<<1, 64, 0, stream>>>(counts, offsets, nmt, tiles);
  scatter_kernel<<<NROWS / 256, 256, 0, stream>>>(topk_idx, offsets, cursors, perm, rowexp, pos);
  gather_lora13_kernel<<<NROWS, 256, 0, stream>>>(x, A1, A3, perm, rowexp, Xg, t1g, t3g);
  gemm1_dual<<<MAX_MT * (HID / BN), 256, 0, stream>>>(Xg, W1b, W3b, b1, b3, B1, B3, t1g, t3g,
                                                      offsets, nmt, tiles, gb);
  lora2_kernel<<<NROWS, 256, 0, stream>>>(gb, A2, rowexp, t2g);
  gemm2_kernel<<<MAX_MT * (DIM / BN), 256, 0, stream>>>(gb, W2b, b2, B2, t2g,
                                                        offsets, nmt, tiles, ye);
  combine_kernel<<<T_TOK, 256, 0, stream>>>(ye, pos, topk_gate, out);
}

// Round 7
// 592.671 us; speedup vs baseline: 1.1643x; 1.0123x over previous
//
#include <hip/hip_runtime.h>

#define DIM 1024
#define HID 2048
#define NE 8
#define LR 16
#define T_TOK 2048
#define NROWS 4096
#define BM 128
#define BN 64
#define BK 64
#define MAX_MT 40
#define ROWS_PAD (NROWS + BM)
#define WELEMS (NE * HID * DIM)   // 16.78M elems per weight tensor

typedef __attribute__((ext_vector_type(8))) short bf16x8;
typedef __attribute__((ext_vector_type(4))) float f32x4;

__device__ __forceinline__ unsigned short f2bf(float f) {
  unsigned u = __builtin_bit_cast(unsigned, f);
  u += 0x7FFFu + ((u >> 16) & 1u);
  return (unsigned short)(u >> 16);
}

__device__ __forceinline__ void gload_lds16(const void* g, void* l) {
  __builtin_amdgcn_global_load_lds(
      (const __attribute__((address_space(1))) unsigned int*)g,
      (__attribute__((address_space(3))) unsigned int*)l, 16, 0, 0);
}

// ---------------- weight fp32 -> bf16 convert (all three in one) -----------
__global__ void wconv3_kernel(const float* __restrict__ W1, const float* __restrict__ W2,
                              const float* __restrict__ W3,
                              unsigned short* __restrict__ o1, unsigned short* __restrict__ o2,
                              unsigned short* __restrict__ o3) {
  for (long long i = (long long)(blockIdx.x * 256 + threadIdx.x) * 8; i < 3LL * WELEMS;
       i += (long long)gridDim.x * 256 * 8) {
    int which = (int)(i / WELEMS);
    int idx = (int)(i - (long long)which * WELEMS);
    const float* f = (which == 0) ? W1 : (which == 1) ? W2 : W3;
    unsigned short* o = (which == 0) ? o1 : (which == 1) ? o2 : o3;
    float4 a = *(const float4*)(f + idx);
    float4 b = *(const float4*)(f + idx + 4);
    ushort4 h0, h1;
    h0.x = f2bf(a.x); h0.y = f2bf(a.y); h0.z = f2bf(a.z); h0.w = f2bf(a.w);
    h1.x = f2bf(b.x); h1.y = f2bf(b.y); h1.z = f2bf(b.z); h1.w = f2bf(b.w);
    *(ushort4*)(o + idx) = h0;
    *(ushort4*)(o + idx + 4) = h1;
  }
}

// ---------------- routing: logits -> top2 -> gates -------------------------
__global__ void routing_kernel(const float* __restrict__ x, const float* __restrict__ Wg,
                               int* __restrict__ counts, int* __restrict__ topk_idx,
                               float* __restrict__ topk_gate) {
  int t = blockIdx.x * 4 + (threadIdx.x >> 6);
  int lane = threadIdx.x & 63;
  const float* xr = x + (size_t)t * DIM;
  float xa[16];
#pragma unroll
  for (int i = 0; i < 16; i++) xa[i] = xr[lane + 64 * i];
  float lg[NE];
#pragma unroll
  for (int e = 0; e < NE; e++) {
    const float* wr_ = Wg + e * DIM;
    float s = 0.f;
#pragma unroll
    for (int i = 0; i < 16; i++) s += xa[i] * wr_[lane + 64 * i];
#pragma unroll
    for (int off = 32; off > 0; off >>= 1) s += __shfl_xor(s, off);
    lg[e] = s;
  }
  if (lane == 0) {
    int i0 = 0;
#pragma unroll
    for (int e = 1; e < NE; e++) if (lg[e] > lg[i0]) i0 = e;
    int i1 = (i0 == 0) ? 1 : 0;
#pragma unroll
    for (int e = 0; e < NE; e++) if (e != i0 && lg[e] > lg[i1]) i1 = e;
    float e1 = __expf(lg[i1] - lg[i0]);
    float inv = 1.f / (1.f + e1);
    topk_idx[2 * t] = i0;
    topk_idx[2 * t + 1] = i1;
    topk_gate[2 * t] = inv;
    topk_gate[2 * t + 1] = e1 * inv;
    atomicAdd(&counts[i0], 1);
    atomicAdd(&counts[i1], 1);
  }
}

// ---------------- scan: offsets + tile schedule ----------------------------
__global__ void scan_kernel(const int* __restrict__ counts, int* __restrict__ offsets,
                            int* __restrict__ nmt, int* __restrict__ tiles) {
  if (threadIdx.x == 0) {
    int off = 0, nt = 0;
    for (int e = 0; e < NE; e++) {
      offsets[e] = off;
      int c = counts[e];
      for (int mm = 0; mm * BM < c; mm++) tiles[nt++] = (e << 16) | mm;
      off += c;
    }
    offsets[NE] = off;
    nmt[0] = nt;
  }
}

// ---------------- scatter: (t,slot) -> compact row -------------------------
__global__ void scatter_kernel(const int* __restrict__ topk_idx,
                               const int* __restrict__ offsets, int* __restrict__ cursors,
                               int* __restrict__ perm, int* __restrict__ rowexp,
                               int* __restrict__ pos) {
  int i = blockIdx.x * 256 + threadIdx.x;
  int e = topk_idx[i];
  int r = offsets[e] + atomicAdd(&cursors[e], 1);
  perm[r] = i >> 1;
  rowexp[r] = e;
  pos[i] = r;
}

// ---------------- gather x rows (bf16) + t1=xA1^T, t3=xA3^T ----------------
__global__ void gather_lora13_kernel(const float* __restrict__ x,
                                     const float* __restrict__ A1, const float* __restrict__ A3,
                                     const int* __restrict__ perm, const int* __restrict__ rowexp,
                                     unsigned short* __restrict__ Xg,
                                     float* __restrict__ t1g, float* __restrict__ t3g) {
  __shared__ float xs[DIM];
  int r = blockIdx.x;
  int t = perm[r], e = rowexp[r];
  int tid = threadIdx.x;
  float4 v = ((const float4*)(x + (size_t)t * DIM))[tid];
  ((float4*)xs)[tid] = v;
  ushort4 hv;
  hv.x = f2bf(v.x); hv.y = f2bf(v.y); hv.z = f2bf(v.z); hv.w = f2bf(v.w);
  ((ushort4*)(Xg + (size_t)r * DIM))[tid] = hv;
  __syncthreads();
  int w = tid >> 6, lane = tid & 63;
  const float* A = ((w < 2) ? A1 : A3) + (size_t)e * LR * DIM + (size_t)((w & 1) * 8) * DIM;
  float* tout = ((w < 2) ? t1g : t3g) + (size_t)r * LR + (w & 1) * 8;
  float acc[8];
#pragma unroll
  for (int j = 0; j < 8; j++) acc[j] = 0.f;
  for (int i = 0; i < 16; i++) {
    float xv = xs[lane + 64 * i];
#pragma unroll
    for (int j = 0; j < 8; j++) acc[j] += xv * A[(size_t)j * DIM + lane + 64 * i];
  }
#pragma unroll
  for (int j = 0; j < 8; j++) {
    float s = acc[j];
#pragma unroll
    for (int off = 32; off > 0; off >>= 1) s += __shfl_xor(s, off);
    if (lane == 0) tout[j] = s;
  }
}

// ---------------- t2 = g A2^T ----------------------------------------------
__global__ void lora2_kernel(const unsigned short* __restrict__ gb,
                             const float* __restrict__ A2, const int* __restrict__ rowexp,
                             float* __restrict__ t2g) {
  __shared__ float gs[HID];
  int r = blockIdx.x, tid = threadIdx.x;
  int e = rowexp[r];
  uint4 raw = ((const uint4*)(gb + (size_t)r * HID))[tid];
  unsigned u[4] = {raw.x, raw.y, raw.z, raw.w};
#pragma unroll
  for (int k = 0; k < 4; k++) {
    gs[tid * 8 + 2 * k] = __builtin_bit_cast(float, u[k] << 16);
    gs[tid * 8 + 2 * k + 1] = __builtin_bit_cast(float, u[k] & 0xffff0000u);
  }
  __syncthreads();
  int w = tid >> 6, lane = tid & 63;
  const float* A = A2 + (size_t)e * LR * HID + (size_t)(w * 4) * HID;
  float acc[4];
#pragma unroll
  for (int j = 0; j < 4; j++) acc[j] = 0.f;
  for (int i = 0; i < HID / 64; i++) {
    float xv = gs[lane + 64 * i];
#pragma unroll
    for (int j = 0; j < 4; j++) acc[j] += xv * A[(size_t)j * HID + lane + 64 * i];
  }
#pragma unroll
  for (int j = 0; j < 4; j++) {
    float s = acc[j];
#pragma unroll
    for (int off = 32; off > 0; off >>= 1) s += __shfl_xor(s, off);
    if (lane == 0) t2g[(size_t)r * LR + w * 4 + j] = s;
  }
}

// ---------------- GEMM1: g = silu(Xg W1^T + lora + b1) * (Xg W3^T + lora + b3)
// m97-style: single 32KB LDS buffer, 2 barriers/K-step, gload_lds16, XOR swizzle.
__global__ __launch_bounds__(256, 4) void gemm1_dual(
    const unsigned short* __restrict__ Xg,
    const unsigned short* __restrict__ W1b, const unsigned short* __restrict__ W3b,
    const float* __restrict__ b1, const float* __restrict__ b3,
    const float* __restrict__ B1l, const float* __restrict__ B3l,
    const float* __restrict__ t1g, const float* __restrict__ t3g,
    const int* __restrict__ offsets, const int* __restrict__ nmt,
    const int* __restrict__ tiles,
    unsigned short* __restrict__ g) {
  int ntid = blockIdx.x & 31;   // HID/BN = 32
  int slot = blockIdx.x >> 5;
  if (slot >= nmt[0]) return;
  int tl = tiles[slot];
  int e = tl >> 16, mtile = tl & 0xffff;
  int row0 = offsets[e] + mtile * BM;
  int rowEnd = offsets[e + 1];
  int col0 = ntid * BN;

  __shared__ __align__(16) char smem[32768];  // 16K A + 8K B1 + 8K B3
  unsigned short* As = (unsigned short*)smem;
  unsigned short* B1s = (unsigned short*)(smem + 16384);
  unsigned short* B3s = (unsigned short*)(smem + 24576);

  int tid = threadIdx.x, lane = tid & 63, w = tid >> 6;
  int wr = w >> 1, wc = w & 1;
  int srow = lane >> 3;                         // 0..7
  int sperm = ((lane & 7) ^ srow) * 8;          // pre-swizzled global col (elems)
  int lxor = (lane & 7) << 3;                   // read-side XOR (elems)

  f32x4 acc1[4][2], acc3[4][2];
#pragma unroll
  for (int i = 0; i < 4; i++)
#pragma unroll
    for (int j = 0; j < 2; j++)
#pragma unroll
      for (int k = 0; k < 4; k++) { acc1[i][j][k] = 0.f; acc3[i][j][k] = 0.f; }

  const unsigned short* Ag = Xg + (size_t)row0 * DIM;
  const unsigned short* W1e = W1b + ((size_t)e * HID + col0) * DIM;
  const unsigned short* W3e = W3b + ((size_t)e * HID + col0) * DIM;

  const int NT1 = DIM / BK;  // 16
  for (int kt = 0; kt < NT1; kt++) {
    int kc = kt * BK + sperm;
#pragma unroll
    for (int it = 0; it < 4; it++)
      gload_lds16(Ag + (size_t)(it * 32 + w * 8 + srow) * DIM + kc, As + (it * 32 + w * 8) * BK);
#pragma unroll
    for (int it = 0; it < 2; it++) {
      gload_lds16(W1e + (size_t)(it * 32 + w * 8 + srow) * DIM + kc, B1s + (it * 32 + w * 8) * BK);
      gload_lds16(W3e + (size_t)(it * 32 + w * 8 + srow) * DIM + kc, B3s + (it * 32 + w * 8) * BK);
    }
    __syncthreads();
#pragma unroll
    for (int kk = 0; kk < 2; kk++) {
      int kx = (kk * 32 + (lane >> 4) * 8) ^ lxor;
      bf16x8 a[4];
#pragma unroll
      for (int mm = 0; mm < 4; mm++)
        a[mm] = *(const bf16x8*)(As + (wr * 64 + mm * 16 + (lane & 15)) * BK + kx);
#pragma unroll
      for (int nn = 0; nn < 2; nn++) {
        bf16x8 bv1 = *(const bf16x8*)(B1s + (wc * 32 + nn * 16 + (lane & 15)) * BK + kx);
        bf16x8 bv3 = *(const bf16x8*)(B3s + (wc * 32 + nn * 16 + (lane & 15)) * BK + kx);
#pragma unroll
        for (int mm = 0; mm < 4; mm++) {
          acc1[mm][nn] = __builtin_amdgcn_mfma_f32_16x16x32_bf16(a[mm], bv1, acc1[mm][nn], 0, 0, 0);
          acc3[mm][nn] = __builtin_amdgcn_mfma_f32_16x16x32_bf16(a[mm], bv3, acc3[mm][nn], 0, 0, 0);
        }
      }
    }
    __syncthreads();
  }

  // epilogue: bias + rank-16 lora + silu-gate, store bf16 g
  float* sT1 = (float*)smem;            // 128x17
  float* sT3 = sT1 + 128 * 17;
  float* sC1 = sT3 + 128 * 17;          // 64x17
  float* sC3 = sC1 + 64 * 17;
  float* sb1 = sC3 + 64 * 17;           // 64
  float* sb3 = sb1 + 64;
  for (int i = tid; i < 128 * 16; i += 256) {
    int rr = i >> 4, jj = i & 15;
    sT1[rr * 17 + jj] = t1g[(size_t)(row0 + rr) * LR + jj];
    sT3[rr * 17 + jj] = t3g[(size_t)(row0 + rr) * LR + jj];
  }
  for (int i = tid; i < 64 * 16; i += 256) {
    int rr = i >> 4, jj = i & 15;
    sC1[rr * 17 + jj] = B1l[((size_t)e * HID + col0 + rr) * LR + jj];
    sC3[rr * 17 + jj] = B3l[((size_t)e * HID + col0 + rr) * LR + jj];
  }
  if (tid < 64) {
    sb1[tid] = b1[e * HID + col0 + tid];
    sb3[tid] = b3[e * HID + col0 + tid];
  }
  __syncthreads();
#pragma unroll
  for (int mm = 0; mm < 4; mm++)
#pragma unroll
    for (int nn = 0; nn < 2; nn++) {
      int cl = wc * 32 + nn * 16 + (lane & 15);
      float bias1 = sb1[cl], bias3 = sb3[cl];
#pragma unroll
      for (int j = 0; j < 4; j++) {
        int rl = wr * 64 + mm * 16 + (lane >> 4) * 4 + j;
        float v1 = acc1[mm][nn][j] + bias1;
        float v3 = acc3[mm][nn][j] + bias3;
#pragma unroll
        for (int jj = 0; jj < 16; jj++) {
          v1 += sT1[rl * 17 + jj] * sC1[cl * 17 + jj];
          v3 += sT3[rl * 17 + jj] * sC3[cl * 17 + jj];
        }
        float gg = v1 * v3 / (1.f + __expf(-v1));
        int r = row0 + rl;
        if (r < rowEnd) g[(size_t)r * HID + col0 + cl] = f2bf(gg);
      }
    }
}

// ---------------- GEMM2: ye = g W2^T + lora + b2 ---------------------------
__global__ __launch_bounds__(256, 4) void gemm2_kernel(
    const unsigned short* __restrict__ gb,
    const unsigned short* __restrict__ W2b, const float* __restrict__ b2,
    const float* __restrict__ B2l, const float* __restrict__ t2g,
    const int* __restrict__ offsets, const int* __restrict__ nmt,
    const int* __restrict__ tiles,
    float* __restrict__ ye) {
  int ntid = blockIdx.x & 15;   // DIM/BN = 16
  int slot = blockIdx.x >> 4;
  if (slot >= nmt[0]) return;
  int tl = tiles[slot];
  int e = tl >> 16, mtile = tl & 0xffff;
  int row0 = offsets[e] + mtile * BM;
  int rowEnd = offsets[e + 1];
  int col0 = ntid * BN;

  __shared__ __align__(16) char smem[24576];  // 16K A + 8K B
  unsigned short* As = (unsigned short*)smem;
  unsigned short* Bs = (unsigned short*)(smem + 16384);

  int tid = threadIdx.x, lane = tid & 63, w = tid >> 6;
  int wr = w >> 1, wc = w & 1;
  int srow = lane >> 3;
  int sperm = ((lane & 7) ^ srow) * 8;
  int lxor = (lane & 7) << 3;

  f32x4 acc[4][2];
#pragma unroll
  for (int i = 0; i < 4; i++)
#pragma unroll
    for (int j = 0; j < 2; j++)
#pragma unroll
      for (int k = 0; k < 4; k++) acc[i][j][k] = 0.f;

  const unsigned short* Ag = gb + (size_t)row0 * HID;
  const unsigned short* W2e = W2b + ((size_t)e * DIM + col0) * HID;

  const int NT2 = HID / BK;  // 32
  for (int kt = 0; kt < NT2; kt++) {
    int kc = kt * BK + sperm;
#pragma unroll
    for (int it = 0; it < 4; it++)
      gload_lds16(Ag + (size_t)(it * 32 + w * 8 + srow) * HID + kc, As + (it * 32 + w * 8) * BK);
#pragma unroll
    for (int it = 0; it < 2; it++)
      gload_lds16(W2e + (size_t)(it * 32 + w * 8 + srow) * HID + kc, Bs + (it * 32 + w * 8) * BK);
    __syncthreads();
#pragma unroll
    for (int kk = 0; kk < 2; kk++) {
      int kx = (kk * 32 + (lane >> 4) * 8) ^ lxor;
      bf16x8 a[4];
#pragma unroll
      for (int mm = 0; mm < 4; mm++)
        a[mm] = *(const bf16x8*)(As + (wr * 64 + mm * 16 + (lane & 15)) * BK + kx);
#pragma unroll
      for (int nn = 0; nn < 2; nn++) {
        bf16x8 bv = *(const bf16x8*)(Bs + (wc * 32 + nn * 16 + (lane & 15)) * BK + kx);
#pragma unroll
        for (int mm = 0; mm < 4; mm++)
          acc[mm][nn] = __builtin_amdgcn_mfma_f32_16x16x32_bf16(a[mm], bv, acc[mm][nn], 0, 0, 0);
      }
    }
    __syncthreads();
  }

  float* sT2 = (float*)smem;        // 128x17
  float* sC2 = sT2 + 128 * 17;      // 64x17
  float* sb2 = sC2 + 64 * 17;       // 64
  for (int i = tid; i < 128 * 16; i += 256) {
    int rr = i >> 4, jj = i & 15;
    sT2[rr * 17 + jj] = t2g[(size_t)(row0 + rr) * LR + jj];
  }
  for (int i = tid; i < 64 * 16; i += 256) {
    int rr = i >> 4, jj = i & 15;
    sC2[rr * 17 + jj] = B2l[((size_t)e * DIM + col0 + rr) * LR + jj];
  }
  if (tid < 64) sb2[tid] = b2[e * DIM + col0 + tid];
  __syncthreads();
#pragma unroll
  for (int mm = 0; mm < 4; mm++)
#pragma unroll
    for (int nn = 0; nn < 2; nn++) {
      int cl = wc * 32 + nn * 16 + (lane & 15);
      float bias = sb2[cl];
#pragma unroll
      for (int j = 0; j < 4; j++) {
        int rl = wr * 64 + mm * 16 + (lane >> 4) * 4 + j;
        float v = acc[mm][nn][j] + bias;
#pragma unroll
        for (int jj = 0; jj < 16; jj++) v += sT2[rl * 17 + jj] * sC2[cl * 17 + jj];
        int r = row0 + rl;
        if (r < rowEnd) ye[(size_t)r * DIM + col0 + cl] = v;
      }
    }
}

// ---------------- combine: y[t] = w0*ye[r0] + w1*ye[r1] (fp32 out) ---------
__global__ void combine_kernel(const float* __restrict__ ye, const int* __restrict__ pos,
                               const float* __restrict__ topk_gate,
                               float* __restrict__ out) {
  int t = blockIdx.x, tid = threadIdx.x;
  int r0 = pos[2 * t], r1 = pos[2 * t + 1];
  float w0 = topk_gate[2 * t], w1 = topk_gate[2 * t + 1];
  float4 a = ((const float4*)(ye + (size_t)r0 * DIM))[tid];
  float4 b = ((const float4*)(ye + (size_t)r1 * DIM))[tid];
  float4 o;
  o.x = w0 * a.x + w1 * b.x;
  o.y = w0 * a.y + w1 * b.y;
  o.z = w0 * a.z + w1 * b.z;
  o.w = w0 * a.w + w1 * b.w;
  ((float4*)(out + (size_t)t * DIM))[tid] = o;
}

extern "C" void kernel_launch(void* const* d_in, const int* in_sizes, int n_in,
                              void* d_out, int out_size, void* d_ws, size_t ws_size,
                              hipStream_t stream) {
  (void)in_sizes; (void)n_in; (void)out_size; (void)ws_size;
  const float* x  = (const float*)d_in[0];
  const float* Wg = (const float*)d_in[1];
  const float* W1 = (const float*)d_in[2];
  const float* b1 = (const float*)d_in[3];
  const float* A1 = (const float*)d_in[4];
  const float* B1 = (const float*)d_in[5];
  const float* W2 = (const float*)d_in[6];
  const float* b2 = (const float*)d_in[7];
  const float* A2 = (const float*)d_in[8];
  const float* B2 = (const float*)d_in[9];
  const float* W3 = (const float*)d_in[10];
  const float* b3 = (const float*)d_in[11];
  const float* A3 = (const float*)d_in[12];
  const float* B3 = (const float*)d_in[13];
  float* out = (float*)d_out;

  char* ws = (char*)d_ws;
  int* counts   = (int*)ws;        // 8
  int* cursors  = counts + 8;      // 8
  int* offsets  = cursors + 8;     // 9
  int* nmt      = offsets + 9;     // 1
  int* tiles    = nmt + 1;         // 40
  int* topk_idx = (int*)(ws + 512);
  float* topk_gate = (float*)(ws + 512 + 16384);
  int* perm   = (int*)(ws + 512 + 2 * 16384);
  int* rowexp = (int*)(ws + 512 + 3 * 16384);
  int* pos    = (int*)(ws + 512 + 4 * 16384);
  size_t off = 82432;  // 512 + 5*16384, 256-aligned
  unsigned short* Xg = (unsigned short*)(ws + off); off += (size_t)ROWS_PAD * DIM * 2;
  unsigned short* gb = (unsigned short*)(ws + off); off += (size_t)ROWS_PAD * HID * 2;
  float* t1g = (float*)(ws + off); off += (size_t)ROWS_PAD * LR * 4;
  float* t3g = (float*)(ws + off); off += (size_t)ROWS_PAD * LR * 4;
  float* t2g = (float*)(ws + off); off += (size_t)ROWS_PAD * LR * 4;
  float* ye  = (float*)(ws + off); off += (size_t)NROWS * DIM * 4;
  unsigned short* W1b = (unsigned short*)(ws + off); off += (size_t)WELEMS * 2;
  unsigned short* W3b = (unsigned short*)(ws + off); off += (size_t)WELEMS * 2;
  unsigned short* W2b = (unsigned short*)(ws + off); off += (size_t)WELEMS * 2;

  hipMemsetAsync(d_ws, 0, 512, stream);
  wconv3_kernel<<<8192, 256, 0, stream>>>(W1, W2, W3, W1b, W2b, W3b);
  routing_kernel<<<T_TOK / 4, 256, 0, stream>>>(x, Wg, counts, topk_idx, topk_gate);
  scan_kernel<<<1, 64, 0, stream>>>(counts, offsets, nmt, tiles);
  scatter_kernel<<<NROWS / 256, 256, 0, stream>>>(topk_idx, offsets, cursors, perm, rowexp, pos);
  gather_lora13_kernel<<<NROWS, 256, 0, stream>>>(x, A1, A3, perm, rowexp, Xg, t1g, t3g);
  gemm1_dual<<<MAX_MT * (HID / BN), 256, 0, stream>>>(Xg, W1b, W3b, b1, b3, B1, B3, t1g, t3g,
                                                      offsets, nmt, tiles, gb);
  lora2_kernel<<<NROWS, 256, 0, stream>>>(gb, A2, rowexp, t2g);
  gemm2_kernel<<<MAX_MT * (DIM / BN), 256, 0, stream>>>(gb, W2b, b2, B2, t2g,
                                                        offsets, nmt, tiles, ye);
  combine_kernel<<<T_TOK, 256, 0, stream>>>(ye, pos, topk_gate, out);
}